// Round 6
// baseline (75.121 us; speedup 1.0000x reference)
//
#include <hip/hip_runtime.h>

// Problem constants (from reference)
constexpr int B = 8;
constexpr int N = 8192;
constexpr int K = 2048;
constexpr int C = 64;
constexpr int NS = 32;            // N_SAMPLE
#define RAD2 0.0625f              // RADIUS^2, exact in fp32

typedef float  fx4 __attribute__((ext_vector_type(4)));
typedef int    ix4 __attribute__((ext_vector_type(4)));

// ---------------------------------------------------------------------------
// Kernel A v4: ball query, one wave per centroid, 128 points per iteration
// (unroll-by-2: halves the number of latency-chained loop iterations).
// Exact reference arithmetic: d2 = (|c|^2 + |p|^2) - 2*c.p, fp32, contract
// off, numpy add order. Selection = first NS in-radius indices ascending;
// pad with first hit (or 0).
// ---------------------------------------------------------------------------
__global__ __launch_bounds__(128) void ballquery_gp_kernel(
    const float* __restrict__ points,     // (B, N, 3)
    const float* __restrict__ centroids,  // (B, K, 3)
    float* __restrict__ gp_out,           // (B, 3, K, NS)
    int* __restrict__ idx_ws)             // (B, K, NS)
{
#pragma clang fp contract(off)
    const int wave = (blockIdx.x * blockDim.x + threadIdx.x) >> 6;
    const int lane = threadIdx.x & 63;
    if (wave >= B * K) return;
    const int b = wave >> 11;            // K = 2048
    const int k = wave & (K - 1);

    const float* cptr = centroids + (size_t)(b * K + k) * 3;
    const float c0 = cptr[0], c1 = cptr[1], c2 = cptr[2];
    const float cc = (c0 * c0 + c1 * c1) + c2 * c2;

    const float* pbase = points + (size_t)b * N * 3;
    int* idxrow = idx_ws + (size_t)wave * NS;
    float* gpb = gp_out + ((size_t)b * 3 * K + k) * NS;

    const unsigned long long below_mask = (lane == 63) ? ~0ull >> 1
                                                       : (1ull << lane) - 1ull;

    int count = 0;
    int idx0 = 0;

    // prefetched current 128 points: lane and lane+64
    float a0 = pbase[lane * 3 + 0];
    float a1 = pbase[lane * 3 + 1];
    float a2 = pbase[lane * 3 + 2];
    float e0 = pbase[(lane + 64) * 3 + 0];
    float e1 = pbase[(lane + 64) * 3 + 1];
    float e2 = pbase[(lane + 64) * 3 + 2];

    for (int base = 0; base < N; base += 128) {
        // prefetch next 128 (wraps on last iter; values unused)
        const bool more = (base + 128 < N);
        const int nlo = more ? (base + 128 + lane) : lane;
        const int nhi = more ? (base + 192 + lane) : lane;
        const float na0 = pbase[nlo * 3 + 0];
        const float na1 = pbase[nlo * 3 + 1];
        const float na2 = pbase[nlo * 3 + 2];
        const float ne0 = pbase[nhi * 3 + 0];
        const float ne1 = pbase[nhi * 3 + 1];
        const float ne2 = pbase[nhi * 3 + 2];

        // low 64
        const float ppA = (a0 * a0 + a1 * a1) + a2 * a2;
        const float cpA = (c0 * a0 + c1 * a1) + c2 * a2;
        const float d2A = (cc + ppA) - 2.0f * cpA;
        // high 64
        const float ppE = (e0 * e0 + e1 * e1) + e2 * e2;
        const float cpE = (c0 * e0 + c1 * e1) + c2 * e2;
        const float d2E = (cc + ppE) - 2.0f * cpE;

        const bool hitA = d2A < RAD2;
        const bool hitE = d2E < RAD2;
        const unsigned long long mlo = __ballot(hitA);
        const unsigned long long mhi = __ballot(hitE);
        const int clo = __popcll(mlo);

        if (hitA) {
            const int pos = count + __popcll(mlo & below_mask);
            if (pos < NS) {
                idxrow[pos] = base + lane;
                gpb[0 * K * NS + pos] = (a0 - c0) * 4.0f;
                gpb[1 * K * NS + pos] = (a1 - c1) * 4.0f;
                gpb[2 * K * NS + pos] = (a2 - c2) * 4.0f;
            }
        }
        if (hitE) {
            const int pos = count + clo + __popcll(mhi & below_mask);
            if (pos < NS) {
                idxrow[pos] = base + 64 + lane;
                gpb[0 * K * NS + pos] = (e0 - c0) * 4.0f;
                gpb[1 * K * NS + pos] = (e1 - c1) * 4.0f;
                gpb[2 * K * NS + pos] = (e2 - c2) * 4.0f;
            }
        }
        if (count == 0) {
            if (mlo != 0ull)      idx0 = base + __builtin_ctzll(mlo);
            else if (mhi != 0ull) idx0 = base + 64 + __builtin_ctzll(mhi);
        }
        count += clo + __popcll(mhi);
        if (count >= NS) break;  // wave-uniform
        a0 = na0; a1 = na1; a2 = na2;
        e0 = ne0; e1 = ne1; e2 = ne2;
    }

    // Padding: slots [min(count,NS), NS) get idx0's point
    const int cnt = count < NS ? count : NS;
    if (lane >= cnt && lane < NS) {
        const float p0 = pbase[idx0 * 3 + 0];
        const float p1 = pbase[idx0 * 3 + 1];
        const float p2 = pbase[idx0 * 3 + 2];
        idxrow[lane] = idx0;
        gpb[0 * K * NS + lane] = (p0 - c0) * 4.0f;
        gpb[1 * K * NS + lane] = (p1 - c1) * 4.0f;
        gpb[2 * K * NS + lane] = (p2 - c2) * 4.0f;
    }
}

// ---------------------------------------------------------------------------
// Kernel B (unchanged from R5): one block per (b,c); 32 KB feature row in
// LDS; idx int4 prefetch; nontemporal streaming stores.
// ---------------------------------------------------------------------------
__global__ __launch_bounds__(1024) void gather_feats_lds(
    const float* __restrict__ features,  // (B, C, N)
    const int* __restrict__ idx_ws,      // (B, K, NS)
    float* __restrict__ nf_out)          // (B, C, K, NS)
{
    __shared__ float row[N];  // 32 KB
    const int bc = blockIdx.x;
    const int t = threadIdx.x;

    {
        const fx4* frow4 = reinterpret_cast<const fx4*>(features + (size_t)bc * N);
        fx4* row4 = reinterpret_cast<fx4*>(row);
#pragma unroll
        for (int j = 0; j < 2; ++j)
            row4[t + j * 1024] = __builtin_nontemporal_load(&frow4[t + j * 1024]);
    }
    __syncthreads();

    const int b = bc >> 6;               // C = 64
    const int* idxb = idx_ws + (size_t)b * K * NS;
    float* outb = nf_out + (size_t)bc * K * NS;

    ix4 iv = *reinterpret_cast<const ix4*>(idxb + (size_t)t * 4);
#pragma unroll
    for (int j = 0; j < 16; ++j) {
        const int g = j * 1024 + t;
        ix4 ivn;
        if (j < 15)
            ivn = *reinterpret_cast<const ix4*>(idxb + (size_t)(g + 1024) * 4);
        fx4 v;
        v.x = row[iv.x];
        v.y = row[iv.y];
        v.z = row[iv.z];
        v.w = row[iv.w];
        __builtin_nontemporal_store(v, reinterpret_cast<fx4*>(outb + (size_t)g * 4));
        if (j < 15) iv = ivn;
    }
}

extern "C" void kernel_launch(void* const* d_in, const int* in_sizes, int n_in,
                              void* d_out, int out_size, void* d_ws, size_t ws_size,
                              hipStream_t stream) {
    const float* points    = (const float*)d_in[0];
    const float* centroids = (const float*)d_in[1];
    const float* features  = (const float*)d_in[2];
    float* out = (float*)d_out;

    float* gp_out = out;                              // B*3*K*NS floats
    float* nf_out = out + (size_t)B * 3 * K * NS;     // B*C*K*NS floats
    int* idx_ws = (int*)d_ws;                         // 2 MB

    const int waves = B * K;                          // 16384

    // Kernel A (real)
    hipLaunchKernelGGL(ballquery_gp_kernel, dim3(waves / 2), dim3(128), 0, stream,
                       points, centroids, gp_out, idx_ws);

    // --- TIMING PROBE: duplicate A writing to scratch (ws) only. ---
    // dur(this round) - dur(next round, probe removed) == A's duration.
    // Needs 2MB(idx real) .. +6MB gp2 +2MB idx2 = 16 MB of ws headroom.
    if (ws_size >= (size_t)16 << 20) {
        float* gp2 = (float*)((char*)d_ws + ((size_t)4 << 20));   // 6 MB
        int* idx2  = (int*)((char*)d_ws + ((size_t)12 << 20));    // 2 MB
        hipLaunchKernelGGL(ballquery_gp_kernel, dim3(waves / 2), dim3(128), 0, stream,
                           points, centroids, gp2, idx2);
    }

    // Kernel B
    hipLaunchKernelGGL(gather_feats_lds, dim3(B * C), dim3(1024), 0, stream,
                       features, idx_ws, nf_out);
}

// Round 7
// 51.822 us; speedup vs baseline: 1.4496x; 1.4496x over previous
//
#include <hip/hip_runtime.h>

// Problem constants (from reference)
constexpr int B = 8;
constexpr int N = 8192;
constexpr int K = 2048;
constexpr int C = 64;
constexpr int NS = 32;            // N_SAMPLE
#define RAD2 0.0625f              // RADIUS^2, exact in fp32

typedef float  fx4 __attribute__((ext_vector_type(4)));
typedef int    ix4 __attribute__((ext_vector_type(4)));

// ---------------------------------------------------------------------------
// Kernel A v5: ball query, one wave per centroid, 128 points/iter.
// Lean scan: loop body only computes d2, ballots, records the two 64-bit hit
// masks to LDS (lane 0), updates count, early-exits at count>=NS. All output
// work deferred to an epilogue: lanes 0..31 locate their j-th hit in the
// recorded masks (broadcast LDS reads), reload that point (L1-hot), and do
// fully coalesced idx + 3-plane gp stores.
// Exact reference arithmetic: d2 = (|c|^2 + |p|^2) - 2*c.p, fp32, contract
// off, numpy add order. Selection = first NS in-radius indices ascending;
// pad with first hit (or point 0 if none).
// ---------------------------------------------------------------------------
__global__ __launch_bounds__(128) void ballquery_gp_kernel(
    const float* __restrict__ points,     // (B, N, 3)
    const float* __restrict__ centroids,  // (B, K, 3)
    float* __restrict__ gp_out,           // (B, 3, K, NS)
    int* __restrict__ idx_ws)             // (B, K, NS)
{
#pragma clang fp contract(off)
    __shared__ unsigned long long masks_s[2][N / 64];  // 2 waves x 128 groups
    const int wave = (blockIdx.x * blockDim.x + threadIdx.x) >> 6;
    const int lane = threadIdx.x & 63;
    if (wave >= B * K) return;
    const int b = wave >> 11;            // K = 2048
    const int k = wave & (K - 1);
    unsigned long long* mk = masks_s[threadIdx.x >> 6];

    const float* cptr = centroids + (size_t)(b * K + k) * 3;
    const float c0 = cptr[0], c1 = cptr[1], c2 = cptr[2];
    const float cc = (c0 * c0 + c1 * c1) + c2 * c2;

    const float* pbase = points + (size_t)b * N * 3;

    int count = 0;

    // prefetched current 128 points: lane and lane+64
    float a0 = pbase[lane * 3 + 0];
    float a1 = pbase[lane * 3 + 1];
    float a2 = pbase[lane * 3 + 2];
    float e0 = pbase[(lane + 64) * 3 + 0];
    float e1 = pbase[(lane + 64) * 3 + 1];
    float e2 = pbase[(lane + 64) * 3 + 2];

    int g = 0;  // 64-point groups recorded
    for (int base = 0; base < N; base += 128) {
        // prefetch next 128 (wraps on last iter; values unused)
        const bool more = (base + 128 < N);
        const int nlo = more ? (base + 128 + lane) : lane;
        const int nhi = more ? (base + 192 + lane) : lane;
        const float na0 = pbase[nlo * 3 + 0];
        const float na1 = pbase[nlo * 3 + 1];
        const float na2 = pbase[nlo * 3 + 2];
        const float ne0 = pbase[nhi * 3 + 0];
        const float ne1 = pbase[nhi * 3 + 1];
        const float ne2 = pbase[nhi * 3 + 2];

        const float ppA = (a0 * a0 + a1 * a1) + a2 * a2;
        const float cpA = (c0 * a0 + c1 * a1) + c2 * a2;
        const float d2A = (cc + ppA) - 2.0f * cpA;
        const float ppE = (e0 * e0 + e1 * e1) + e2 * e2;
        const float cpE = (c0 * e0 + c1 * e1) + c2 * e2;
        const float d2E = (cc + ppE) - 2.0f * cpE;

        const unsigned long long mlo = __ballot(d2A < RAD2);
        const unsigned long long mhi = __ballot(d2E < RAD2);
        if (lane == 0) {
            mk[g] = mlo;
            mk[g + 1] = mhi;
        }
        count += __popcll(mlo) + __popcll(mhi);
        g += 2;
        if (count >= NS) break;  // wave-uniform
        a0 = na0; a1 = na1; a2 = na2;
        e0 = ne0; e1 = ne1; e2 = ne2;
    }

    // Epilogue: lanes 0..31 each produce output slot `lane`.
    if (lane < NS) {
        const int cnt = count < NS ? count : NS;
        int i = 0;
        if (count > 0) {
            const int target = (lane < cnt) ? lane : 0;  // pad slots use hit #0
            int running = 0;
            int gg = 0;
            unsigned long long m;
            for (;; ++gg) {  // terminates: sum(popc) = count > target
                m = mk[gg];
                const int c = __popcll(m);
                if (running + c > target) break;
                running += c;
            }
            int r = target - running;
            for (int t = 0; t < r; ++t) m &= m - 1;  // clear r lowest set bits
            i = gg * 64 + __builtin_ctzll(m);
        }
        const float p0 = pbase[i * 3 + 0];
        const float p1 = pbase[i * 3 + 1];
        const float p2 = pbase[i * 3 + 2];
        idx_ws[(size_t)wave * NS + lane] = i;
        float* gpb = gp_out + ((size_t)b * 3 * K + k) * NS;
        gpb[0 * K * NS + lane] = (p0 - c0) * 4.0f;
        gpb[1 * K * NS + lane] = (p1 - c1) * 4.0f;
        gpb[2 * K * NS + lane] = (p2 - c2) * 4.0f;
    }
}

// ---------------------------------------------------------------------------
// Kernel B (unchanged): one block per (b,c); 32 KB feature row in LDS;
// idx int4 prefetch; nontemporal streaming stores.
// ---------------------------------------------------------------------------
__global__ __launch_bounds__(1024) void gather_feats_lds(
    const float* __restrict__ features,  // (B, C, N)
    const int* __restrict__ idx_ws,      // (B, K, NS)
    float* __restrict__ nf_out)          // (B, C, K, NS)
{
    __shared__ float row[N];  // 32 KB
    const int bc = blockIdx.x;
    const int t = threadIdx.x;

    {
        const fx4* frow4 = reinterpret_cast<const fx4*>(features + (size_t)bc * N);
        fx4* row4 = reinterpret_cast<fx4*>(row);
#pragma unroll
        for (int j = 0; j < 2; ++j)
            row4[t + j * 1024] = __builtin_nontemporal_load(&frow4[t + j * 1024]);
    }
    __syncthreads();

    const int b = bc >> 6;               // C = 64
    const int* idxb = idx_ws + (size_t)b * K * NS;
    float* outb = nf_out + (size_t)bc * K * NS;

    ix4 iv = *reinterpret_cast<const ix4*>(idxb + (size_t)t * 4);
#pragma unroll
    for (int j = 0; j < 16; ++j) {
        const int g = j * 1024 + t;
        ix4 ivn;
        if (j < 15)
            ivn = *reinterpret_cast<const ix4*>(idxb + (size_t)(g + 1024) * 4);
        fx4 v;
        v.x = row[iv.x];
        v.y = row[iv.y];
        v.z = row[iv.z];
        v.w = row[iv.w];
        __builtin_nontemporal_store(v, reinterpret_cast<fx4*>(outb + (size_t)g * 4));
        if (j < 15) iv = ivn;
    }
}

extern "C" void kernel_launch(void* const* d_in, const int* in_sizes, int n_in,
                              void* d_out, int out_size, void* d_ws, size_t ws_size,
                              hipStream_t stream) {
    const float* points    = (const float*)d_in[0];
    const float* centroids = (const float*)d_in[1];
    const float* features  = (const float*)d_in[2];
    float* out = (float*)d_out;

    float* gp_out = out;                              // B*3*K*NS floats
    float* nf_out = out + (size_t)B * 3 * K * NS;     // B*C*K*NS floats
    int* idx_ws = (int*)d_ws;                         // 2 MB

    const int waves = B * K;                          // 16384

    hipLaunchKernelGGL(ballquery_gp_kernel, dim3(waves / 2), dim3(128), 0, stream,
                       points, centroids, gp_out, idx_ws);

    hipLaunchKernelGGL(gather_feats_lds, dim3(B * C), dim3(1024), 0, stream,
                       features, idx_ws, nf_out);
}